// Round 14
// baseline (69.797 us; speedup 1.0000x reference)
//
#include <hip/hip_runtime.h>
#include <cmath>

namespace {
constexpr int B_ = 2, K_ = 4, D_ = 128, L_ = 4096, N_ = 16, R_ = 8, C_ = 40;
constexpr int CHUNK = 32, NCH = L_ / CHUNK;   // 128 chunks of 32
constexpr float LOG2E = 1.44269504f;
}

#if __has_builtin(__builtin_amdgcn_exp2f)
#define FEXP2(x) __builtin_amdgcn_exp2f(x)
#else
#define FEXP2(x) exp2f(x)
#endif

// ===========================================================================
// k1: projections (r7 + unroll16 + dual-half stores). 256 blocks x 640 thr;
// wave w computes 4 channels (w0-5 kv: dts+B, w6-9 q: C). X via VMEM, W via
// LDS broadcast. After shfl_xor both halves hold the sum -> each stores 2 j's.
// ===========================================================================
__global__ __launch_bounds__(640, 2) void k1_proj(
    const float* __restrict__ qx, const float* __restrict__ kv,
    const float* __restrict__ xw,
    float* __restrict__ dtsT, float* __restrict__ BT, float* __restrict__ CT)
{
    __shared__ float Wt[D_ * C_];   // [d][c]

    const int tid = threadIdx.x;
    const int w = tid >> 6, lane = tid & 63;
    const int dg = lane >> 5, lq = lane & 31;
    int blk = blockIdx.x;
    const int lt = blk & 31; blk >>= 5;
    const int k = blk & 3; const int b = blk >> 2;
    const int bk = b * K_ + k;

    for (int i = tid; i < C_ * D_; i += 640) {
        const int c = i >> 7, d = i & 127;
        Wt[d * C_ + c] = xw[(k * C_ + c) * D_ + d];
    }
    __syncthreads();

    const float* xsrc = (w >= 6) ? qx : kv;
    const int c0 = w * 4;
    float acc[4][4];
    #pragma unroll
    for (int c = 0; c < 4; ++c)
        #pragma unroll
        for (int j = 0; j < 4; ++j) acc[c][j] = 0.f;

    const float* src = xsrc + ((size_t)bk * D_ + dg * 64) * L_ + lt * 128 + 4 * lq;
    #pragma unroll 16
    for (int dd = 0; dd < 64; ++dd) {
        const float4 x = *(const float4*)(src + (size_t)dd * L_);
        const float4 wv = *(const float4*)&Wt[(dg * 64 + dd) * C_ + c0];
        const float* wp = (const float*)&wv;
        #pragma unroll
        for (int c = 0; c < 4; ++c) {
            acc[c][0] = fmaf(x.x, wp[c], acc[c][0]);
            acc[c][1] = fmaf(x.y, wp[c], acc[c][1]);
            acc[c][2] = fmaf(x.z, wp[c], acc[c][2]);
            acc[c][3] = fmaf(x.w, wp[c], acc[c][3]);
        }
    }

    #pragma unroll
    for (int c = 0; c < 4; ++c)
        #pragma unroll
        for (int j = 0; j < 4; ++j)
            acc[c][j] += __shfl_xor(acc[c][j], 32, 64);

    // both halves hold the full sum: dg0 stores j=0,1; dg1 stores j=2,3
    #pragma unroll
    for (int jj = 0; jj < 2; ++jj) {
        const int j = dg * 2 + jj;
        const int l = lt * 128 + 4 * lq + j;
        float4 o; o.x = acc[0][j]; o.y = acc[1][j]; o.z = acc[2][j]; o.w = acc[3][j];
        if (w < 2)
            *(float4*)(dtsT + ((size_t)bk * L_ + l) * R_ + w * 4) = o;
        else if (w < 6)
            *(float4*)(BT + ((size_t)bk * L_ + l) * N_ + (w - 2) * 4) = o;
        else
            *(float4*)(CT + ((size_t)bk * L_ + l) * N_ + (w - 6) * 4) = o;
    }
}

// ===========================================================================
// k2: chunk pass 1 (r7 verbatim). Grid 1024, thread = d, u direct from kv.
// ===========================================================================
__global__ __launch_bounds__(128, 1) void k2_pass1(
    const float* __restrict__ kv, const float* __restrict__ dtsT,
    const float* __restrict__ BT, const float* __restrict__ alg,
    const float* __restrict__ dtw, const float* __restrict__ dtb,
    float* __restrict__ hend, float* __restrict__ Ssum)
{
    __shared__ float dts_s[CHUNK * R_];   // 1 KB
    __shared__ float B_s[CHUNK * N_];     // 2 KB

    const int tid = threadIdx.x;
    const int d = tid;
    const int blk = blockIdx.x;
    const int ch = blk & (NCH - 1);
    const int bk = blk >> 7;
    const int k = bk & 3;

    {
        const float* src = dtsT + ((size_t)bk * L_ + ch * CHUNK) * R_;
        if (tid < 64) *(float4*)&dts_s[4 * tid] = *(const float4*)(src + 4 * tid);
        const float* bsrc = BT + ((size_t)bk * L_ + ch * CHUNK) * N_;
        *(float4*)&B_s[4 * tid] = *(const float4*)(bsrc + 4 * tid);
    }

    float uu[CHUNK];
    {
        const float4* up = (const float4*)(kv + ((size_t)bk * D_ + d) * L_ + ch * CHUNK);
        #pragma unroll
        for (int j = 0; j < 8; ++j) {
            const float4 v = up[j];
            uu[4*j] = v.x; uu[4*j+1] = v.y; uu[4*j+2] = v.z; uu[4*j+3] = v.w;
        }
    }

    float dtwr[R_];
    {
        const float* p = dtw + ((size_t)k * D_ + d) * R_;
        *(float4*)&dtwr[0] = *(const float4*)p;
        *(float4*)&dtwr[4] = *(const float4*)(p + 4);
    }
    const float bias = dtb[k * D_ + d];
    float A2[N_];
    {
        const float* ap = alg + ((size_t)k * D_ + d) * N_;
        #pragma unroll
        for (int j = 0; j < 4; ++j) {
            float4 a = *(const float4*)(ap + 4 * j);
            A2[4*j]   = -__expf(a.x) * LOG2E; A2[4*j+1] = -__expf(a.y) * LOG2E;
            A2[4*j+2] = -__expf(a.z) * LOG2E; A2[4*j+3] = -__expf(a.w) * LOG2E;
        }
    }
    __syncthreads();

    float h[N_];
    #pragma unroll
    for (int n = 0; n < N_; ++n) h[n] = 0.f;
    float sd = 0.f;

    #pragma unroll
    for (int l = 0; l < CHUNK; ++l) {
        float dv[R_];
        *(float4*)&dv[0] = *(const float4*)&dts_s[l * R_];
        *(float4*)&dv[4] = *(const float4*)&dts_s[l * R_ + 4];
        float s = bias;
        #pragma unroll
        for (int r = 0; r < R_; ++r) s = fmaf(dv[r], dtwr[r], s);
        const float e = FEXP2(s * LOG2E);
        const float dlt = (s > 15.f) ? s : __logf(1.f + e);
        sd += dlt;
        const float xb = dlt * uu[l];
        #pragma unroll
        for (int g = 0; g < 4; ++g) {
            const float4 bg = *(const float4*)&B_s[l * N_ + 4 * g];
            h[4*g+0] = fmaf(FEXP2(dlt * A2[4*g+0]), h[4*g+0], xb * bg.x);
            h[4*g+1] = fmaf(FEXP2(dlt * A2[4*g+1]), h[4*g+1], xb * bg.y);
            h[4*g+2] = fmaf(FEXP2(dlt * A2[4*g+2]), h[4*g+2], xb * bg.z);
            h[4*g+3] = fmaf(FEXP2(dlt * A2[4*g+3]), h[4*g+3], xb * bg.w);
        }
    }

    float* hp = hend + (((size_t)bk * NCH + ch) * D_ + d) * N_;
    #pragma unroll
    for (int j = 0; j < 4; ++j) {
        float4 o; o.x = h[4*j]; o.y = h[4*j+1]; o.z = h[4*j+2]; o.w = h[4*j+3];
        *(float4*)(hp + 4 * j) = o;
    }
    Ssum[((size_t)bk * NCH + ch) * D_ + d] = sd;
}

// ===========================================================================
// k25: serial chunk chain (r7 verbatim). hend -> hinit exclusive prefix,
// 32-deep batched coalesced loads; exp off the dependence chain.
// ===========================================================================
__global__ __launch_bounds__(64, 2) void k25_chain(
    const float* __restrict__ alg, const float* __restrict__ Ssum,
    const float* __restrict__ hend, float* __restrict__ hinit)
{
    const int tg = blockIdx.x * 64 + threadIdx.x;   // 16384 threads
    const int n = tg & 15;
    const int d = (tg >> 4) & 127;
    const int bk = tg >> 11;
    const int k = bk & 3;

    const float A2 = -__expf(alg[((size_t)k * D_ + d) * N_ + n]) * LOG2E;
    float h = 0.f;
    for (int c0 = 0; c0 < NCH; c0 += 32) {
        float he[32], ss[32];
        #pragma unroll
        for (int j = 0; j < 32; ++j) {
            const size_t si = ((size_t)bk * NCH + c0 + j) * D_ + d;
            he[j] = hend[si * N_ + n];
            ss[j] = Ssum[si];
        }
        #pragma unroll
        for (int j = 0; j < 32; ++j) {
            const size_t si = ((size_t)bk * NCH + c0 + j) * D_ + d;
            hinit[si * N_ + n] = h;
            h = fmaf(FEXP2(ss[j] * A2), h, he[j]);
        }
    }
}

// ===========================================================================
// k3: pass-2 (r7 minus y_s). y(+u*Ds) accumulated in a per-thread float4 and
// stored directly every 4th step (thread owns 32 contiguous floats; L2 merges
// the 16B runs into full lines). LDS 5 KB, one barrier.
// ===========================================================================
__global__ __launch_bounds__(128, 1) void k3_pass2(
    const float* __restrict__ kv, const float* __restrict__ dtsT,
    const float* __restrict__ BT, const float* __restrict__ CT,
    const float* __restrict__ alg, const float* __restrict__ dtw,
    const float* __restrict__ dtb, const float* __restrict__ DsG,
    const float* __restrict__ hinit, float* __restrict__ out)
{
    __shared__ float dts_s[CHUNK * R_];
    __shared__ float B_s[CHUNK * N_];
    __shared__ float C_s[CHUNK * N_];
    const int tid = threadIdx.x;
    const int d = tid;
    const int blk = blockIdx.x;
    const int ch = blk & (NCH - 1);
    const int bk = blk >> 7;
    const int k = bk & 3;

    {
        const float* src = dtsT + ((size_t)bk * L_ + ch * CHUNK) * R_;
        if (tid < 64) *(float4*)&dts_s[4 * tid] = *(const float4*)(src + 4 * tid);
        const float* bsrc = BT + ((size_t)bk * L_ + ch * CHUNK) * N_;
        *(float4*)&B_s[4 * tid] = *(const float4*)(bsrc + 4 * tid);
        const float* csrc = CT + ((size_t)bk * L_ + ch * CHUNK) * N_;
        *(float4*)&C_s[4 * tid] = *(const float4*)(csrc + 4 * tid);
    }
    float uu[CHUNK];
    {
        const float4* up = (const float4*)(kv + ((size_t)bk * D_ + d) * L_ + ch * CHUNK);
        #pragma unroll
        for (int j = 0; j < 8; ++j) {
            const float4 v = up[j];
            uu[4*j] = v.x; uu[4*j+1] = v.y; uu[4*j+2] = v.z; uu[4*j+3] = v.w;
        }
    }
    float dtwr[R_];
    {
        const float* p = dtw + ((size_t)k * D_ + d) * R_;
        *(float4*)&dtwr[0] = *(const float4*)p;
        *(float4*)&dtwr[4] = *(const float4*)(p + 4);
    }
    const float bias = dtb[k * D_ + d];
    const float Dv = DsG[k * D_ + d];
    float A2[N_];
    {
        const float* ap = alg + ((size_t)k * D_ + d) * N_;
        #pragma unroll
        for (int j = 0; j < 4; ++j) {
            float4 a = *(const float4*)(ap + 4 * j);
            A2[4*j]   = -__expf(a.x) * LOG2E; A2[4*j+1] = -__expf(a.y) * LOG2E;
            A2[4*j+2] = -__expf(a.z) * LOG2E; A2[4*j+3] = -__expf(a.w) * LOG2E;
        }
    }
    float h[N_];
    {
        const float* hp = hinit + (((size_t)bk * NCH + ch) * D_ + d) * N_;
        #pragma unroll
        for (int j = 0; j < 4; ++j) {
            float4 v = *(const float4*)(hp + 4 * j);
            h[4*j] = v.x; h[4*j+1] = v.y; h[4*j+2] = v.z; h[4*j+3] = v.w;
        }
    }
    __syncthreads();

    float* orow = out + ((size_t)bk * D_ + d) * L_ + ch * CHUNK;
    float4 yv;
    #pragma unroll
    for (int l = 0; l < CHUNK; ++l) {
        float dv[R_];
        *(float4*)&dv[0] = *(const float4*)&dts_s[l * R_];
        *(float4*)&dv[4] = *(const float4*)&dts_s[l * R_ + 4];
        float s = bias;
        #pragma unroll
        for (int r = 0; r < R_; ++r) s = fmaf(dv[r], dtwr[r], s);
        const float e = FEXP2(s * LOG2E);
        const float dlt = (s > 15.f) ? s : __logf(1.f + e);
        const float xb = dlt * uu[l];
        float p0 = 0.f, p1 = 0.f;
        #pragma unroll
        for (int g = 0; g < 4; ++g) {
            const float4 bg = *(const float4*)&B_s[l * N_ + 4 * g];
            const float4 cg4 = *(const float4*)&C_s[l * N_ + 4 * g];
            h[4*g+0] = fmaf(FEXP2(dlt * A2[4*g+0]), h[4*g+0], xb * bg.x);
            p0 = fmaf(h[4*g+0], cg4.x, p0);
            h[4*g+1] = fmaf(FEXP2(dlt * A2[4*g+1]), h[4*g+1], xb * bg.y);
            p1 = fmaf(h[4*g+1], cg4.y, p1);
            h[4*g+2] = fmaf(FEXP2(dlt * A2[4*g+2]), h[4*g+2], xb * bg.z);
            p0 = fmaf(h[4*g+2], cg4.z, p0);
            h[4*g+3] = fmaf(FEXP2(dlt * A2[4*g+3]), h[4*g+3], xb * bg.w);
            p1 = fmaf(h[4*g+3], cg4.w, p1);
        }
        ((float*)&yv)[l & 3] = fmaf(uu[l], Dv, p0 + p1);
        if ((l & 3) == 3) *(float4*)(orow + (l - 3)) = yv;
    }
}

extern "C" void kernel_launch(void* const* d_in, const int* in_sizes, int n_in,
                              void* d_out, int out_size, void* d_ws, size_t ws_size,
                              hipStream_t stream)
{
    const float* qx  = (const float*)d_in[0];
    const float* kv  = (const float*)d_in[1];
    const float* xw  = (const float*)d_in[2];
    const float* dtw = (const float*)d_in[3];
    const float* dtb = (const float*)d_in[4];
    const float* alg = (const float*)d_in[5];
    const float* Ds  = (const float*)d_in[6];
    float* out = (float*)d_out;

    const size_t sz_dts = (size_t)B_ * K_ * L_ * R_;        //   262,144
    const size_t sz_bc  = (size_t)B_ * K_ * L_ * N_;        //   524,288
    const size_t sz_h   = (size_t)B_ * K_ * NCH * D_ * N_;  // 2,097,152
    const size_t sz_ss  = (size_t)B_ * K_ * NCH * D_;       //   131,072
    const size_t need = (sz_dts + 2 * sz_bc + 2 * sz_h + sz_ss) * sizeof(float);
    if (ws_size < need) return;   // ~22.5 MB

    float* dts   = (float*)d_ws;
    float* BTp   = dts + sz_dts;
    float* CTp   = BTp + sz_bc;
    float* hend  = CTp + sz_bc;
    float* hinit = hend + sz_h;
    float* Ssm   = hinit + sz_h;

    k1_proj<<<B_ * K_ * 32, 640, 0, stream>>>(qx, kv, xw, dts, BTp, CTp);
    k2_pass1<<<B_ * K_ * NCH, 128, 0, stream>>>(kv, dts, BTp, alg, dtw, dtb, hend, Ssm);
    k25_chain<<<256, 64, 0, stream>>>(alg, Ssm, hend, hinit);
    k3_pass2<<<B_ * K_ * NCH, 128, 0, stream>>>(kv, dts, BTp, CTp, alg, dtw, dtb, Ds, hinit, out);
}

// Round 15
// 68.619 us; speedup vs baseline: 1.0172x; 1.0172x over previous
//
#include <hip/hip_runtime.h>
#include <cmath>

namespace {
constexpr int B_ = 2, K_ = 4, D_ = 128, L_ = 4096, N_ = 16, R_ = 8, C_ = 40;
constexpr int CHUNK = 32, NCH = L_ / CHUNK;   // 128 chunks of 32
constexpr int US = CHUNK + 1;                 // 33: stride for u/y tiles
constexpr float LOG2E = 1.44269504f;
}

#if __has_builtin(__builtin_amdgcn_exp2f)
#define FEXP2(x) __builtin_amdgcn_exp2f(x)
#else
#define FEXP2(x) exp2f(x)
#endif

// ===========================================================================
// k1: projections (r7 verbatim). 256 blocks x 640 thr (10 waves); wave w
// computes 4 channels (w0-5 kv: dts+B, w6-9 q: C). X via VMEM, W via LDS
// broadcast - pipe-balanced.
// ===========================================================================
__global__ __launch_bounds__(640, 2) void k1_proj(
    const float* __restrict__ qx, const float* __restrict__ kv,
    const float* __restrict__ xw,
    float* __restrict__ dtsT, float* __restrict__ BT, float* __restrict__ CT)
{
    __shared__ float Wt[D_ * C_];   // [d][c]

    const int tid = threadIdx.x;
    const int w = tid >> 6, lane = tid & 63;
    const int dg = lane >> 5, lq = lane & 31;
    int blk = blockIdx.x;
    const int lt = blk & 31; blk >>= 5;
    const int k = blk & 3; const int b = blk >> 2;
    const int bk = b * K_ + k;

    for (int i = tid; i < C_ * D_; i += 640) {
        const int c = i >> 7, d = i & 127;
        Wt[d * C_ + c] = xw[(k * C_ + c) * D_ + d];
    }
    __syncthreads();

    const float* xsrc = (w >= 6) ? qx : kv;
    const int c0 = w * 4;
    float acc[4][4];
    #pragma unroll
    for (int c = 0; c < 4; ++c)
        #pragma unroll
        for (int j = 0; j < 4; ++j) acc[c][j] = 0.f;

    const float* src = xsrc + ((size_t)bk * D_ + dg * 64) * L_ + lt * 128 + 4 * lq;
    #pragma unroll 8
    for (int dd = 0; dd < 64; ++dd) {
        const float4 x = *(const float4*)(src + (size_t)dd * L_);
        const float4 wv = *(const float4*)&Wt[(dg * 64 + dd) * C_ + c0];
        const float* wp = (const float*)&wv;
        #pragma unroll
        for (int c = 0; c < 4; ++c) {
            acc[c][0] = fmaf(x.x, wp[c], acc[c][0]);
            acc[c][1] = fmaf(x.y, wp[c], acc[c][1]);
            acc[c][2] = fmaf(x.z, wp[c], acc[c][2]);
            acc[c][3] = fmaf(x.w, wp[c], acc[c][3]);
        }
    }

    #pragma unroll
    for (int c = 0; c < 4; ++c)
        #pragma unroll
        for (int j = 0; j < 4; ++j)
            acc[c][j] += __shfl_xor(acc[c][j], 32, 64);

    if (dg == 0) {
        #pragma unroll
        for (int j = 0; j < 4; ++j) {
            const int l = lt * 128 + 4 * lq + j;
            float4 o; o.x = acc[0][j]; o.y = acc[1][j]; o.z = acc[2][j]; o.w = acc[3][j];
            if (w < 2)
                *(float4*)(dtsT + ((size_t)bk * L_ + l) * R_ + w * 4) = o;
            else if (w < 6)
                *(float4*)(BT + ((size_t)bk * L_ + l) * N_ + (w - 2) * 4) = o;
            else
                *(float4*)(CT + ((size_t)bk * L_ + l) * N_ + (w - 6) * 4) = o;
        }
    }
}

// ===========================================================================
// k2: pass-1, n-split. Block = 256 thr: thread (d, nh) = (tid>>1, tid&1);
// pair lanes (2d, 2d+1) split the 16 n-states (8 each). u staged once in
// stride-33 LDS (conflict-free, pair-broadcast reads). 16 waves/CU.
// ===========================================================================
__global__ __launch_bounds__(256, 4) void k2_pass1(
    const float* __restrict__ kv, const float* __restrict__ dtsT,
    const float* __restrict__ BT, const float* __restrict__ alg,
    const float* __restrict__ dtw, const float* __restrict__ dtb,
    float* __restrict__ hend, float* __restrict__ Ssum)
{
    __shared__ float u_s[D_ * US];        // 16.9 KB
    __shared__ float dts_s[CHUNK * R_];   // 1 KB
    __shared__ float B_s[CHUNK * N_];     // 2 KB

    const int tid = threadIdx.x;
    const int d = tid >> 1, nh = tid & 1;
    const int blk = blockIdx.x;
    const int ch = blk & (NCH - 1);
    const int bk = blk >> 7;
    const int k = bk & 3;

    // stage u: 128 rows x 32 floats (coalesced global, scalar LDS writes)
    {
        const float* base = kv + ((size_t)bk * D_) * L_ + ch * CHUNK;
        #pragma unroll
        for (int p = 0; p < 4; ++p) {
            const int f = tid + p * 256;
            const int row = f >> 3, c4 = (f & 7) * 4;
            const float4 v = *(const float4*)(base + (size_t)row * L_ + c4);
            float* pp = &u_s[row * US + c4];
            pp[0] = v.x; pp[1] = v.y; pp[2] = v.z; pp[3] = v.w;
        }
    }
    {
        const float* src = dtsT + ((size_t)bk * L_ + ch * CHUNK) * R_;
        if (tid < 64) *(float4*)&dts_s[4 * tid] = *(const float4*)(src + 4 * tid);
        const float* bsrc = BT + ((size_t)bk * L_ + ch * CHUNK) * N_;
        if (tid < 128) *(float4*)&B_s[4 * tid] = *(const float4*)(bsrc + 4 * tid);
    }

    float dtwr[R_];
    {
        const float* p = dtw + ((size_t)k * D_ + d) * R_;
        *(float4*)&dtwr[0] = *(const float4*)p;
        *(float4*)&dtwr[4] = *(const float4*)(p + 4);
    }
    const float bias = dtb[k * D_ + d];
    float A2[8];
    {
        const float* ap = alg + ((size_t)k * D_ + d) * N_ + nh * 8;
        #pragma unroll
        for (int j = 0; j < 2; ++j) {
            float4 a = *(const float4*)(ap + 4 * j);
            A2[4*j]   = -__expf(a.x) * LOG2E; A2[4*j+1] = -__expf(a.y) * LOG2E;
            A2[4*j+2] = -__expf(a.z) * LOG2E; A2[4*j+3] = -__expf(a.w) * LOG2E;
        }
    }
    __syncthreads();

    float h[8];
    #pragma unroll
    for (int n = 0; n < 8; ++n) h[n] = 0.f;
    float sd = 0.f;

    #pragma unroll
    for (int l = 0; l < CHUNK; ++l) {
        float dv[R_];
        *(float4*)&dv[0] = *(const float4*)&dts_s[l * R_];
        *(float4*)&dv[4] = *(const float4*)&dts_s[l * R_ + 4];
        float s = bias;
        #pragma unroll
        for (int r = 0; r < R_; ++r) s = fmaf(dv[r], dtwr[r], s);
        const float e = FEXP2(s * LOG2E);
        const float dlt = (s > 15.f) ? s : __logf(1.f + e);
        sd += dlt;
        const float xb = dlt * u_s[d * US + l];
        #pragma unroll
        for (int g = 0; g < 2; ++g) {
            const float4 bg = *(const float4*)&B_s[l * N_ + nh * 8 + 4 * g];
            h[4*g+0] = fmaf(FEXP2(dlt * A2[4*g+0]), h[4*g+0], xb * bg.x);
            h[4*g+1] = fmaf(FEXP2(dlt * A2[4*g+1]), h[4*g+1], xb * bg.y);
            h[4*g+2] = fmaf(FEXP2(dlt * A2[4*g+2]), h[4*g+2], xb * bg.z);
            h[4*g+3] = fmaf(FEXP2(dlt * A2[4*g+3]), h[4*g+3], xb * bg.w);
        }
    }

    float* hp = hend + (((size_t)bk * NCH + ch) * D_ + d) * N_ + nh * 8;
    {
        float4 o0; o0.x = h[0]; o0.y = h[1]; o0.z = h[2]; o0.w = h[3];
        float4 o1; o1.x = h[4]; o1.y = h[5]; o1.z = h[6]; o1.w = h[7];
        *(float4*)hp = o0;
        *(float4*)(hp + 4) = o1;
    }
    if (nh == 0) Ssum[((size_t)bk * NCH + ch) * D_ + d] = sd;
}

// ===========================================================================
// k25: serial chunk chain (r7 verbatim). hend -> hinit exclusive prefix,
// 32-deep batched coalesced loads; exp off the dependence chain.
// ===========================================================================
__global__ __launch_bounds__(64, 2) void k25_chain(
    const float* __restrict__ alg, const float* __restrict__ Ssum,
    const float* __restrict__ hend, float* __restrict__ hinit)
{
    const int tg = blockIdx.x * 64 + threadIdx.x;   // 16384 threads
    const int n = tg & 15;
    const int d = (tg >> 4) & 127;
    const int bk = tg >> 11;
    const int k = bk & 3;

    const float A2 = -__expf(alg[((size_t)k * D_ + d) * N_ + n]) * LOG2E;
    float h = 0.f;
    for (int c0 = 0; c0 < NCH; c0 += 32) {
        float he[32], ss[32];
        #pragma unroll
        for (int j = 0; j < 32; ++j) {
            const size_t si = ((size_t)bk * NCH + c0 + j) * D_ + d;
            he[j] = hend[si * N_ + n];
            ss[j] = Ssum[si];
        }
        #pragma unroll
        for (int j = 0; j < 32; ++j) {
            const size_t si = ((size_t)bk * NCH + c0 + j) * D_ + d;
            hinit[si * N_ + n] = h;
            h = fmaf(FEXP2(ss[j] * A2), h, he[j]);
        }
    }
}

// ===========================================================================
// k3: pass-2, n-split. Pair lanes (2d,2d+1) each own 8 n-states; partial
// y-sums combined with one shfl_xor(p,1); nh==0 writes the stride-33 y tile;
// coalesced d-major flush (r7 pattern). 16 waves/CU.
// ===========================================================================
__global__ __launch_bounds__(256, 4) void k3_pass2(
    const float* __restrict__ kv, const float* __restrict__ dtsT,
    const float* __restrict__ BT, const float* __restrict__ CT,
    const float* __restrict__ alg, const float* __restrict__ dtw,
    const float* __restrict__ dtb, const float* __restrict__ DsG,
    const float* __restrict__ hinit, float* __restrict__ out)
{
    __shared__ float u_s[D_ * US];        // 16.9 KB
    __shared__ float y_s[D_ * US];        // 16.9 KB
    __shared__ float dts_s[CHUNK * R_];   // 1 KB
    __shared__ float B_s[CHUNK * N_];     // 2 KB
    __shared__ float C_s[CHUNK * N_];     // 2 KB

    const int tid = threadIdx.x;
    const int d = tid >> 1, nh = tid & 1;
    const int blk = blockIdx.x;
    const int ch = blk & (NCH - 1);
    const int bk = blk >> 7;
    const int k = bk & 3;

    {
        const float* base = kv + ((size_t)bk * D_) * L_ + ch * CHUNK;
        #pragma unroll
        for (int p = 0; p < 4; ++p) {
            const int f = tid + p * 256;
            const int row = f >> 3, c4 = (f & 7) * 4;
            const float4 v = *(const float4*)(base + (size_t)row * L_ + c4);
            float* pp = &u_s[row * US + c4];
            pp[0] = v.x; pp[1] = v.y; pp[2] = v.z; pp[3] = v.w;
        }
    }
    {
        const float* src = dtsT + ((size_t)bk * L_ + ch * CHUNK) * R_;
        if (tid < 64) *(float4*)&dts_s[4 * tid] = *(const float4*)(src + 4 * tid);
        const float* bsrc = BT + ((size_t)bk * L_ + ch * CHUNK) * N_;
        const float* csrc = CT + ((size_t)bk * L_ + ch * CHUNK) * N_;
        if (tid < 128) *(float4*)&B_s[4 * tid] = *(const float4*)(bsrc + 4 * tid);
        else           *(float4*)&C_s[4 * (tid - 128)] = *(const float4*)(csrc + 4 * (tid - 128));
    }

    float dtwr[R_];
    {
        const float* p = dtw + ((size_t)k * D_ + d) * R_;
        *(float4*)&dtwr[0] = *(const float4*)p;
        *(float4*)&dtwr[4] = *(const float4*)(p + 4);
    }
    const float bias = dtb[k * D_ + d];
    const float Dv = DsG[k * D_ + d];
    float A2[8];
    {
        const float* ap = alg + ((size_t)k * D_ + d) * N_ + nh * 8;
        #pragma unroll
        for (int j = 0; j < 2; ++j) {
            float4 a = *(const float4*)(ap + 4 * j);
            A2[4*j]   = -__expf(a.x) * LOG2E; A2[4*j+1] = -__expf(a.y) * LOG2E;
            A2[4*j+2] = -__expf(a.z) * LOG2E; A2[4*j+3] = -__expf(a.w) * LOG2E;
        }
    }
    float h[8];
    {
        const float* hp = hinit + (((size_t)bk * NCH + ch) * D_ + d) * N_ + nh * 8;
        float4 v0 = *(const float4*)hp;
        float4 v1 = *(const float4*)(hp + 4);
        h[0] = v0.x; h[1] = v0.y; h[2] = v0.z; h[3] = v0.w;
        h[4] = v1.x; h[5] = v1.y; h[6] = v1.z; h[7] = v1.w;
    }
    __syncthreads();

    #pragma unroll
    for (int l = 0; l < CHUNK; ++l) {
        float dv[R_];
        *(float4*)&dv[0] = *(const float4*)&dts_s[l * R_];
        *(float4*)&dv[4] = *(const float4*)&dts_s[l * R_ + 4];
        float s = bias;
        #pragma unroll
        for (int r = 0; r < R_; ++r) s = fmaf(dv[r], dtwr[r], s);
        const float e = FEXP2(s * LOG2E);
        const float dlt = (s > 15.f) ? s : __logf(1.f + e);
        const float ul = u_s[d * US + l];
        const float xb = dlt * ul;
        float p0 = 0.f, p1 = 0.f;
        #pragma unroll
        for (int g = 0; g < 2; ++g) {
            const float4 bg  = *(const float4*)&B_s[l * N_ + nh * 8 + 4 * g];
            const float4 cg4 = *(const float4*)&C_s[l * N_ + nh * 8 + 4 * g];
            h[4*g+0] = fmaf(FEXP2(dlt * A2[4*g+0]), h[4*g+0], xb * bg.x);
            p0 = fmaf(h[4*g+0], cg4.x, p0);
            h[4*g+1] = fmaf(FEXP2(dlt * A2[4*g+1]), h[4*g+1], xb * bg.y);
            p1 = fmaf(h[4*g+1], cg4.y, p1);
            h[4*g+2] = fmaf(FEXP2(dlt * A2[4*g+2]), h[4*g+2], xb * bg.z);
            p0 = fmaf(h[4*g+2], cg4.z, p0);
            h[4*g+3] = fmaf(FEXP2(dlt * A2[4*g+3]), h[4*g+3], xb * bg.w);
            p1 = fmaf(h[4*g+3], cg4.w, p1);
        }
        float p = p0 + p1;
        p += __shfl_xor(p, 1, 64);          // combine the two n-halves (same wave)
        if (nh == 0) y_s[d * US + l] = fmaf(ul, Dv, p);
    }
    __syncthreads();

    // flush d-major coalesced: 128 rows x 8 float4 (scalar LDS reads)
    #pragma unroll
    for (int p = 0; p < 4; ++p) {
        const int f = tid + p * 256;
        const int row = f >> 3, j4 = (f & 7) * 4;
        const float* yp = &y_s[row * US + j4];
        float4 o; o.x = yp[0]; o.y = yp[1]; o.z = yp[2]; o.w = yp[3];
        *(float4*)(out + ((size_t)bk * D_ + row) * L_ + ch * CHUNK + j4) = o;
    }
}

extern "C" void kernel_launch(void* const* d_in, const int* in_sizes, int n_in,
                              void* d_out, int out_size, void* d_ws, size_t ws_size,
                              hipStream_t stream)
{
    const float* qx  = (const float*)d_in[0];
    const float* kv  = (const float*)d_in[1];
    const float* xw  = (const float*)d_in[2];
    const float* dtw = (const float*)d_in[3];
    const float* dtb = (const float*)d_in[4];
    const float* alg = (const float*)d_in[5];
    const float* Ds  = (const float*)d_in[6];
    float* out = (float*)d_out;

    const size_t sz_dts = (size_t)B_ * K_ * L_ * R_;        //   262,144
    const size_t sz_bc  = (size_t)B_ * K_ * L_ * N_;        //   524,288
    const size_t sz_h   = (size_t)B_ * K_ * NCH * D_ * N_;  // 2,097,152
    const size_t sz_ss  = (size_t)B_ * K_ * NCH * D_;       //   131,072
    const size_t need = (sz_dts + 2 * sz_bc + 2 * sz_h + sz_ss) * sizeof(float);
    if (ws_size < need) return;   // ~22.5 MB

    float* dts   = (float*)d_ws;
    float* BTp   = dts + sz_dts;
    float* CTp   = BTp + sz_bc;
    float* hend  = CTp + sz_bc;
    float* hinit = hend + sz_h;
    float* Ssm   = hinit + sz_h;

    k1_proj<<<B_ * K_ * 32, 640, 0, stream>>>(qx, kv, xw, dts, BTp, CTp);
    k2_pass1<<<B_ * K_ * NCH, 256, 0, stream>>>(kv, dts, BTp, alg, dtw, dtb, hend, Ssm);
    k25_chain<<<256, 64, 0, stream>>>(alg, Ssm, hend, hinit);
    k3_pass2<<<B_ * K_ * NCH, 256, 0, stream>>>(kv, dts, BTp, CTp, alg, dtw, dtb, Ds, hinit, out);
}